// Round 1
// baseline (399.102 us; speedup 1.0000x reference)
//
#include <hip/hip_runtime.h>
#include <hip/hip_bf16.h>

typedef unsigned short u16;
typedef unsigned int   u32;

#define NP     4096
#define KCH    32
#define NCH    (NP*KCH)          // 131072
#define RELN   (NCH*3)           // 393216
#define HBASE  RELN
#define CLBASE (RELN + NCH*256)  // 33947648

// ws layout (bytes)
#define WS_W2T   0               // [512 n][512 k] bf16
#define WS_W3T   524288          // [256 n][512 k] bf16
#define WS_W1AT  786432          // [512 n][256 k] bf16
#define WS_F1    1048576         // [4096 p][512 n] f32 (b1 included)

using bf16x8 = __attribute__((ext_vector_type(8))) short;
using f32x4  = __attribute__((ext_vector_type(4))) float;

__device__ inline u16 f2bf(float x) {
  union { float f; u32 u; } v; v.f = x;
  u32 r = v.u + 0x7FFFu + ((v.u >> 16) & 1u);
  return (u16)(r >> 16);
}
__device__ inline u32 pack2(float a, float b) {
  return (u32)f2bf(a) | ((u32)f2bf(b) << 16);
}

// ---------------- K0: weight transpose->bf16 + cluster fill ----------------
__global__ __launch_bounds__(256) void k_prep(const float* __restrict__ W1,
                                              const float* __restrict__ W2,
                                              const float* __restrict__ W3,
                                              u16* __restrict__ w1at,
                                              u16* __restrict__ w2t,
                                              u16* __restrict__ w3t,
                                              float* __restrict__ out) {
  int b = blockIdx.x, t = threadIdx.x;
  if (b >= 512) {
    int idx = (b - 512) * 256 + t;
    out[CLBASE + idx] = (float)(idx >> 5);
    return;
  }
  __shared__ float tile[32][33];
  const float* src; u16* dst; int pitchN, pitchK, kt, nt;
  if (b < 128)      { src = W1; dst = w1at; pitchN = 512; pitchK = 256; kt = b >> 4;          nt = b & 15; }
  else if (b < 384) { int bb = b - 128; src = W2; dst = w2t; pitchN = 512; pitchK = 512; kt = bb >> 4; nt = bb & 15; }
  else              { int bb = b - 384; src = W3; dst = w3t; pitchN = 256; pitchK = 512; kt = bb >> 3; nt = bb & 7;  }
  {
    int kk = t >> 3, n4 = (t & 7) * 4;
    const float4 v = *(const float4*)(src + (kt * 32 + kk) * pitchN + nt * 32 + n4);
    tile[kk][n4 + 0] = v.x; tile[kk][n4 + 1] = v.y;
    tile[kk][n4 + 2] = v.z; tile[kk][n4 + 3] = v.w;
  }
  __syncthreads();
  {
    int n = t >> 3, k4 = (t & 7) * 4;
    uint2 o;
    o.x = pack2(tile[k4 + 0][n], tile[k4 + 1][n]);
    o.y = pack2(tile[k4 + 2][n], tile[k4 + 3][n]);
    *(uint2*)(dst + (nt * 32 + n) * pitchK + kt * 32 + k4) = o;
  }
}

// ---------------- K1: relative_points (fp32 exact) ----------------
__global__ __launch_bounds__(128) void k_rel(const float* __restrict__ in_feats,
                                             const float* __restrict__ Wd,
                                             const float* __restrict__ bd,
                                             float* __restrict__ out) {
  int p = blockIdx.x, t = threadIdx.x;
  __shared__ float ne[128];
  ne[t] = in_feats[p * 384 + t];
  __syncthreads();
  if (t < 96) {
    float acc = bd[t];
#pragma unroll 8
    for (int k = 0; k < 128; ++k) acc += ne[k] * Wd[k * 96 + t];
    out[p * 96 + t] = acc;
  }
}

// ---------------- K2: F1 = feat @ W1a + b1 (MFMA) ----------------
__global__ __launch_bounds__(512, 4) void k_f1(const float* __restrict__ in_feats,
                                               const float* __restrict__ b1,
                                               const u16* __restrict__ w1at,
                                               float* __restrict__ F1) {
  int p0 = blockIdx.x * 16;
  int tid = threadIdx.x, lane = tid & 63, w = tid >> 6;
  __shared__ u16 sh_a[16 * 256];   // [16 r][256 k] bf16, XOR-swizzled 16B slots
  __shared__ u16 sh_b[512 * 32];   // [n][32 k] bf16 chunk
  __shared__ float b1s[512];
  b1s[tid] = b1[tid];
  {
    int r = tid >> 5, k0 = (tid & 31) * 8;
    const float4 v0 = *(const float4*)(in_feats + (p0 + r) * 384 + 128 + k0);
    const float4 v1 = *(const float4*)(in_feats + (p0 + r) * 384 + 128 + k0 + 4);
    uint4 o;
    o.x = pack2(v0.x, v0.y); o.y = pack2(v0.z, v0.w);
    o.z = pack2(v1.x, v1.y); o.w = pack2(v1.z, v1.w);
    int slot = (k0 >> 3) ^ (r & 7);
    *(uint4*)(sh_a + r * 256 + slot * 8) = o;
  }
  f32x4 acc[4];
#pragma unroll
  for (int i = 0; i < 4; ++i) acc[i] = f32x4{0.f, 0.f, 0.f, 0.f};
  int nb = w * 64;
  int q8 = (lane >> 4) * 8;
  for (int kc = 0; kc < 256; kc += 32) {
    __syncthreads();
#pragma unroll
    for (int it = 0; it < 4; ++it) {
      int flat = it * 512 + tid, n = flat >> 2, q = flat & 3;
      *(uint4*)(sh_b + n * 32 + q * 8) = *(const uint4*)(w1at + n * 256 + kc + q * 8);
    }
    __syncthreads();
    int row = lane & 15;
    int slot = ((kc + q8) >> 3) ^ (row & 7);
    bf16x8 a = *(const bf16x8*)(sh_a + row * 256 + slot * 8);
#pragma unroll
    for (int nf = 0; nf < 4; ++nf) {
      int n = nb + nf * 16 + (lane & 15);
      bf16x8 bfr = *(const bf16x8*)(sh_b + n * 32 + q8);
      acc[nf] = __builtin_amdgcn_mfma_f32_16x16x32_bf16(a, bfr, acc[nf], 0, 0, 0);
    }
  }
  int col = lane & 15, rb = (lane >> 4) * 4;
#pragma unroll
  for (int nf = 0; nf < 4; ++nf) {
    int n = nb + nf * 16 + col;
#pragma unroll
    for (int i = 0; i < 4; ++i)
      F1[(p0 + rb + i) * 512 + n] = acc[nf][i] + b1s[n];
  }
}

// ---------------- K3: fused h1-build + GEMM2 + GEMM3 ----------------
__global__ __launch_bounds__(512, 4) void k_main(const float* __restrict__ W1,
                                                 const float* __restrict__ b2,
                                                 const float* __restrict__ b3,
                                                 const u16* __restrict__ w2t,
                                                 const u16* __restrict__ w3t,
                                                 const float* __restrict__ F1,
                                                 float* __restrict__ out) {
  int p = blockIdx.x;
  int tid = threadIdx.x, lane = tid & 63, w = tid >> 6;
  __shared__ u16 sh_h[32 * 512];   // h1 then h2, [32 r][512 k] bf16, XOR-swizzled slots
  __shared__ u16 sh_b[512 * 32];   // weight chunk [n][32 k]
  __shared__ float f1s[512], b2s[512], b3s[256], w1bs[3 * 512], rels[96];

  f1s[tid] = F1[p * 512 + tid];
  b2s[tid] = b2[tid];
  if (tid < 256) b3s[tid] = b3[tid];
  w1bs[tid]        = W1[256 * 512 + tid];
  w1bs[tid + 512]  = W1[257 * 512 + tid];
  w1bs[tid + 1024] = W1[258 * 512 + tid];
  if (tid < 96) rels[tid] = out[p * 96 + tid];   // written by k_rel earlier in stream
  __syncthreads();

  // ---- build h1 tile (32 rows x 512) into LDS as bf16 ----
  {
    int r = tid & 31, g = tid >> 5;              // g in 0..15
    float r0 = rels[r * 3 + 0], r1 = rels[r * 3 + 1], r2 = rels[r * 3 + 2];
#pragma unroll
    for (int gg = 0; gg < 8; ++gg) {
      int col = g * 4 + gg * 64;
      const float4 f  = *(const float4*)(f1s + col);
      const float4 w0 = *(const float4*)(w1bs + col);
      const float4 w1 = *(const float4*)(w1bs + 512 + col);
      const float4 w2 = *(const float4*)(w1bs + 1024 + col);
      float v0 = fmaxf(f.x + r0 * w0.x + r1 * w1.x + r2 * w2.x, 0.f);
      float v1 = fmaxf(f.y + r0 * w0.y + r1 * w1.y + r2 * w2.y, 0.f);
      float v2 = fmaxf(f.z + r0 * w0.z + r1 * w1.z + r2 * w2.z, 0.f);
      float v3 = fmaxf(f.w + r0 * w0.w + r1 * w1.w + r2 * w2.w, 0.f);
      uint2 o; o.x = pack2(v0, v1); o.y = pack2(v2, v3);
      int slot = (col >> 3) ^ (r & 7);
      *(uint2*)(sh_h + r * 512 + slot * 8 + (g & 1) * 4) = o;
    }
  }

  // ---- GEMM2: h2 = relu(h1 @ W2 + b2), acc in regs ----
  f32x4 acc2[2][4];
#pragma unroll
  for (int mf = 0; mf < 2; ++mf)
#pragma unroll
    for (int nf = 0; nf < 4; ++nf) acc2[mf][nf] = f32x4{0.f, 0.f, 0.f, 0.f};
  int nb = w * 64;
  int q8 = (lane >> 4) * 8;
  for (int kc = 0; kc < 512; kc += 32) {
    __syncthreads();
#pragma unroll
    for (int it = 0; it < 4; ++it) {
      int flat = it * 512 + tid, n = flat >> 2, q = flat & 3;
      *(uint4*)(sh_b + n * 32 + q * 8) = *(const uint4*)(w2t + n * 512 + kc + q * 8);
    }
    __syncthreads();
    bf16x8 a[2];
#pragma unroll
    for (int mf = 0; mf < 2; ++mf) {
      int row = mf * 16 + (lane & 15);
      int slot = ((kc + q8) >> 3) ^ (row & 7);
      a[mf] = *(const bf16x8*)(sh_h + row * 512 + slot * 8);
    }
#pragma unroll
    for (int nf = 0; nf < 4; ++nf) {
      int n = nb + nf * 16 + (lane & 15);
      bf16x8 bfr = *(const bf16x8*)(sh_b + n * 32 + q8);
#pragma unroll
      for (int mf = 0; mf < 2; ++mf)
        acc2[mf][nf] = __builtin_amdgcn_mfma_f32_16x16x32_bf16(a[mf], bfr, acc2[mf][nf], 0, 0, 0);
    }
  }
  __syncthreads();   // all sh_h reads done

  // ---- h2 -> LDS (relu + bf16, swizzled) ----
  {
    int col = lane & 15, rq = (lane >> 4) * 4;
#pragma unroll
    for (int mf = 0; mf < 2; ++mf)
#pragma unroll
      for (int nf = 0; nf < 4; ++nf) {
        int n = nb + nf * 16 + col;
#pragma unroll
        for (int i = 0; i < 4; ++i) {
          int r = mf * 16 + rq + i;
          float v = fmaxf(acc2[mf][nf][i] + b2s[n], 0.f);
          sh_h[r * 512 + (((n >> 3) ^ (r & 7)) << 3) + (n & 7)] = f2bf(v);
        }
      }
  }

  // ---- GEMM3: h3 = relu(h2 @ W3 + b3) ----
  f32x4 acc3[2][2];
#pragma unroll
  for (int mf = 0; mf < 2; ++mf)
#pragma unroll
    for (int nf = 0; nf < 2; ++nf) acc3[mf][nf] = f32x4{0.f, 0.f, 0.f, 0.f};
  int nb3 = w * 32;
  for (int kc = 0; kc < 512; kc += 32) {
    __syncthreads();
#pragma unroll
    for (int it = 0; it < 2; ++it) {
      int flat = it * 512 + tid, n = flat >> 2, q = flat & 3;
      *(uint4*)(sh_b + n * 32 + q * 8) = *(const uint4*)(w3t + n * 512 + kc + q * 8);
    }
    __syncthreads();
    bf16x8 a[2];
#pragma unroll
    for (int mf = 0; mf < 2; ++mf) {
      int row = mf * 16 + (lane & 15);
      int slot = ((kc + q8) >> 3) ^ (row & 7);
      a[mf] = *(const bf16x8*)(sh_h + row * 512 + slot * 8);
    }
#pragma unroll
    for (int nf = 0; nf < 2; ++nf) {
      int n = nb3 + nf * 16 + (lane & 15);
      bf16x8 bfr = *(const bf16x8*)(sh_b + n * 32 + q8);
#pragma unroll
      for (int mf = 0; mf < 2; ++mf)
        acc3[mf][nf] = __builtin_amdgcn_mfma_f32_16x16x32_bf16(a[mf], bfr, acc3[mf][nf], 0, 0, 0);
    }
  }

  // ---- epilogue: write h ----
  {
    int col = lane & 15, rq = (lane >> 4) * 4;
#pragma unroll
    for (int mf = 0; mf < 2; ++mf)
#pragma unroll
      for (int nf = 0; nf < 2; ++nf) {
        int n = nb3 + nf * 16 + col;
#pragma unroll
        for (int i = 0; i < 4; ++i) {
          int r = mf * 16 + rq + i;
          float v = fmaxf(acc3[mf][nf][i] + b3s[n], 0.f);
          out[HBASE + (p * 32 + r) * 256 + n] = v;
        }
      }
  }
}

extern "C" void kernel_launch(void* const* d_in, const int* in_sizes, int n_in,
                              void* d_out, int out_size, void* d_ws, size_t ws_size,
                              hipStream_t stream) {
  const float* in_feats = (const float*)d_in[0];
  const float* Wd = (const float*)d_in[1];
  const float* bd = (const float*)d_in[2];
  const float* W1 = (const float*)d_in[3];
  const float* b1 = (const float*)d_in[4];
  const float* W2 = (const float*)d_in[5];
  const float* b2 = (const float*)d_in[6];
  const float* W3 = (const float*)d_in[7];
  const float* b3 = (const float*)d_in[8];
  float* out = (float*)d_out;
  char* ws = (char*)d_ws;
  u16*   w2t  = (u16*)(ws + WS_W2T);
  u16*   w3t  = (u16*)(ws + WS_W3T);
  u16*   w1at = (u16*)(ws + WS_W1AT);
  float* F1   = (float*)(ws + WS_F1);

  k_prep<<<1024, 256, 0, stream>>>(W1, W2, W3, w1at, w2t, w3t, out);
  k_rel<<<4096, 128, 0, stream>>>(in_feats, Wd, bd, out);
  k_f1<<<256, 512, 0, stream>>>(in_feats, b1, w1at, F1);
  k_main<<<4096, 512, 0, stream>>>(W1, b2, b3, w2t, w3t, F1, out);
}

// Round 2
// 272.603 us; speedup vs baseline: 1.4640x; 1.4640x over previous
//
#include <hip/hip_runtime.h>
#include <hip/hip_bf16.h>

typedef unsigned short u16;
typedef unsigned int   u32;

#define NP     4096
#define NCH    131072
#define HBASE  393216            // rel region = 131072*3
#define CLBASE 33947648          // HBASE + 131072*256

// ws layout (bytes)
#define WS_W2F   0               // 512 frags * 1KB  (W2: nb 0..31, kc 0..15, id=nb*16+kc)
#define WS_W3F   524288          // 256 frags * 1KB  (W3: nb 0..15, kc 0..15)
#define WS_W1AF  786432          // 256 frags * 1KB  (W1a: nb 0..31, kc 0..7, id=nb*8+kc)
#define WS_F1    1048576         // [4096][512] f32

using bf16x8 = __attribute__((ext_vector_type(8))) short;
using f32x4  = __attribute__((ext_vector_type(4))) float;

__device__ inline u16 f2bf(float x) {
  union { float f; u32 u; } v; v.f = x;
  u32 r = v.u + 0x7FFFu + ((v.u >> 16) & 1u);
  return (u16)(r >> 16);
}
__device__ inline u32 pack2(float a, float b) {
  return (u32)f2bf(a) | ((u32)f2bf(b) << 16);
}

// ---------------- K0: weights -> bf16 MFMA-fragment layout + cluster fill ----
// Fragment (nb,kc): 64 lanes * 8 bf16 contiguous (1KB). lane l, elem j:
//   W[k = kc*32 + (l>>4)*8 + j][n = nb*16 + (l&15)]
__global__ __launch_bounds__(256) void k_prep(const float* __restrict__ W1,
                                              const float* __restrict__ W2,
                                              const float* __restrict__ W3,
                                              u16* __restrict__ w1af,
                                              u16* __restrict__ w2f,
                                              u16* __restrict__ w3f,
                                              float* __restrict__ out) {
  int b = blockIdx.x, t = threadIdx.x;
  if (b >= 512) {                       // cluster ids
    int idx = (b - 512) * 256 + t;
    out[CLBASE + idx] = (float)(idx >> 5);
    return;
  }
  __shared__ float tile[32][33];
  const float* src; u16* dst; int pitchN, kt, nt, nkc;
  if (b < 128)      { src = W1; dst = w1af; pitchN = 512; kt = b & 7;  nt = b >> 3; nkc = 8;  }
  else if (b < 384) { int bb = b - 128; src = W2; dst = w2f; pitchN = 512; kt = bb & 15; nt = bb >> 4; nkc = 16; }
  else              { int bb = b - 384; src = W3; dst = w3f; pitchN = 256; kt = bb & 15; nt = bb >> 4; nkc = 16; }
  {
    int kk = t >> 3, n4 = (t & 7) * 4;
    const float4 v = *(const float4*)(src + (kt * 32 + kk) * pitchN + nt * 32 + n4);
    tile[kk][n4 + 0] = v.x; tile[kk][n4 + 1] = v.y;
    tile[kk][n4 + 2] = v.z; tile[kk][n4 + 3] = v.w;
  }
  __syncthreads();
  {
    int s = t >> 1, half = t & 1, fr = s >> 6, l = s & 63;
    int n_l = fr * 16 + (l & 15);
    int k_l = (l >> 4) * 8 + half * 4;
    uint2 o;
    o.x = pack2(tile[k_l + 0][n_l], tile[k_l + 1][n_l]);
    o.y = pack2(tile[k_l + 2][n_l], tile[k_l + 3][n_l]);
    int frag_id = (nt * 2 + fr) * nkc + kt;
    *(uint2*)(dst + frag_id * 512 + l * 8 + half * 4) = o;
  }
}

// ---------------- K1: relative_points (fp32 exact), 4 parents/block ---------
__global__ __launch_bounds__(512) void k_rel(const float* __restrict__ in_feats,
                                             const float* __restrict__ Wd,
                                             const float* __restrict__ bd,
                                             float* __restrict__ out) {
  int p0 = blockIdx.x * 4, t = threadIdx.x;
  __shared__ float wd[12288];          // 128 k x 96 n
  __shared__ float ne[512];            // 4 parents x 128
  __shared__ float bds[96];
#pragma unroll
  for (int i = 0; i < 6; ++i)
    *(float4*)(wd + (i * 512 + t) * 4) = *(const float4*)(Wd + (i * 512 + t) * 4);
  { int pp = t >> 7, k = t & 127; ne[t] = in_feats[(p0 + pp) * 384 + k]; }
  if (t < 96) bds[t] = bd[t];
  __syncthreads();
  if (t < 384) {
    int pp = t / 96, c = t - pp * 96;
    float acc = bds[c];
    const float* nep = ne + pp * 128;
#pragma unroll 4
    for (int k = 0; k < 128; ++k) acc += nep[k] * wd[k * 96 + c];
    out[(p0 + pp) * 96 + c] = acc;
  }
}

// ---------------- K2: F1 = feat @ W1a + b1 (MFMA, direct-L2 B frags) --------
__global__ __launch_bounds__(512, 2) void k_f1(const float* __restrict__ in_feats,
                                               const float* __restrict__ b1,
                                               const u16* __restrict__ w1af,
                                               float* __restrict__ F1) {
  int p0 = blockIdx.x * 16;
  int tid = threadIdx.x, lane = tid & 63, w = tid >> 6;
  __shared__ u16 sh_a[16 * 256];       // [16 r][256 k], XOR-swizzled 16B slots
  __shared__ float b1s[512];
  b1s[tid] = b1[tid];
  {
    int r = tid >> 5, k0 = (tid & 31) * 8;
    const float4 v0 = *(const float4*)(in_feats + (p0 + r) * 384 + 128 + k0);
    const float4 v1 = *(const float4*)(in_feats + (p0 + r) * 384 + 128 + k0 + 4);
    uint4 o;
    o.x = pack2(v0.x, v0.y); o.y = pack2(v0.z, v0.w);
    o.z = pack2(v1.x, v1.y); o.w = pack2(v1.z, v1.w);
    int slot = (k0 >> 3) ^ (r & 7);
    *(uint4*)(sh_a + r * 256 + slot * 8) = o;
  }
  __syncthreads();
  f32x4 acc[4];
#pragma unroll
  for (int i = 0; i < 4; ++i) acc[i] = f32x4{0.f, 0.f, 0.f, 0.f};
  int col = lane & 15, q8 = (lane >> 4) * 8;
#pragma unroll
  for (int kc = 0; kc < 8; ++kc) {
    int slot = ((kc * 32 + q8) >> 3) ^ (col & 7);
    bf16x8 a = *(const bf16x8*)(sh_a + col * 256 + slot * 8);
#pragma unroll
    for (int nf = 0; nf < 4; ++nf) {
      bf16x8 bfr = *(const bf16x8*)(w1af + ((w * 4 + nf) * 8 + kc) * 512 + lane * 8);
      acc[nf] = __builtin_amdgcn_mfma_f32_16x16x32_bf16(a, bfr, acc[nf], 0, 0, 0);
    }
  }
  int rb = (lane >> 4) * 4;
#pragma unroll
  for (int nf = 0; nf < 4; ++nf) {
    int n = w * 64 + nf * 16 + col;
#pragma unroll
    for (int i = 0; i < 4; ++i)
      F1[(p0 + rb + i) * 512 + n] = acc[nf][i] + b1s[n];
  }
}

// ---------------- K3: fused h1-build + GEMM2 + GEMM3 (M=128, no staging) ----
__global__ __launch_bounds__(512, 2) void k_main(const float* __restrict__ W1,
                                                 const float* __restrict__ b2,
                                                 const float* __restrict__ b3,
                                                 const u16* __restrict__ w2f,
                                                 const u16* __restrict__ w3f,
                                                 const float* __restrict__ F1,
                                                 float* __restrict__ out) {
  int blk = blockIdx.x;
  int tid = threadIdx.x, lane = tid & 63, w = tid >> 6;
  __shared__ u16 sh_h[128 * 512];      // h1 then h2, XOR-swizzled 16B slots
  __shared__ float f1s[2048], w1bs[1536], b2s[512], b3s[256], rels[384];

  *(float4*)(f1s + tid * 4) = *(const float4*)(F1 + blk * 2048 + tid * 4);
  w1bs[tid]        = W1[131072 + tid];          // W1 rows 256..258
  w1bs[tid + 512]  = W1[131072 + 512 + tid];
  w1bs[tid + 1024] = W1[131072 + 1024 + tid];
  b2s[tid] = b2[tid];
  if (tid < 256) b3s[tid] = b3[tid];
  if (tid < 384) rels[tid] = out[blk * 384 + tid];
  __syncthreads();

  // ---- build h1 (128 x 512) into LDS as bf16 ----
  {
    int rbase = tid & 31, g = tid >> 5;
#pragma unroll
    for (int rr = 0; rr < 128; rr += 32) {
      int r = rr + rbase, pp = r >> 5;
      float r0 = rels[r * 3 + 0], r1 = rels[r * 3 + 1], r2 = rels[r * 3 + 2];
#pragma unroll
      for (int gg = 0; gg < 8; ++gg) {
        int c4 = g * 4 + gg * 64;
        const float4 f  = *(const float4*)(f1s + pp * 512 + c4);
        const float4 w0 = *(const float4*)(w1bs + c4);
        const float4 w1v = *(const float4*)(w1bs + 512 + c4);
        const float4 w2v = *(const float4*)(w1bs + 1024 + c4);
        float v0 = fmaxf(f.x + r0 * w0.x + r1 * w1v.x + r2 * w2v.x, 0.f);
        float v1 = fmaxf(f.y + r0 * w0.y + r1 * w1v.y + r2 * w2v.y, 0.f);
        float v2 = fmaxf(f.z + r0 * w0.z + r1 * w1v.z + r2 * w2v.z, 0.f);
        float v3 = fmaxf(f.w + r0 * w0.w + r1 * w1v.w + r2 * w2v.w, 0.f);
        uint2 o; o.x = pack2(v0, v1); o.y = pack2(v2, v3);
        int slot = (c4 >> 3) ^ (r & 7);
        *(uint2*)(sh_h + r * 512 + slot * 8 + (g & 1) * 4) = o;
      }
    }
  }
  __syncthreads();

  int col = lane & 15, q8 = (lane >> 4) * 8;

  // ---- GEMM2: h2 = relu(h1 @ W2 + b2); barrier-free K-loop ----
  f32x4 acc2[8][4];
#pragma unroll
  for (int mf = 0; mf < 8; ++mf)
#pragma unroll
    for (int nf = 0; nf < 4; ++nf) acc2[mf][nf] = f32x4{0.f, 0.f, 0.f, 0.f};
#pragma unroll 2
  for (int kc = 0; kc < 16; ++kc) {
    bf16x8 bfr[4];
#pragma unroll
    for (int nf = 0; nf < 4; ++nf)
      bfr[nf] = *(const bf16x8*)(w2f + ((w * 4 + nf) * 16 + kc) * 512 + lane * 8);
#pragma unroll
    for (int mf = 0; mf < 8; ++mf) {
      int row = mf * 16 + col;
      int slot = ((kc * 32 + q8) >> 3) ^ (row & 7);
      bf16x8 a = *(const bf16x8*)(sh_h + row * 512 + slot * 8);
#pragma unroll
      for (int nf = 0; nf < 4; ++nf)
        acc2[mf][nf] = __builtin_amdgcn_mfma_f32_16x16x32_bf16(a, bfr[nf], acc2[mf][nf], 0, 0, 0);
    }
  }
  __syncthreads();   // all h1 reads done

  // ---- h2 -> LDS (relu + bf16, swizzled) ----
  {
    int rq = (lane >> 4) * 4;
#pragma unroll
    for (int mf = 0; mf < 8; ++mf)
#pragma unroll
      for (int nf = 0; nf < 4; ++nf) {
        int n = w * 64 + nf * 16 + col;
#pragma unroll
        for (int i = 0; i < 4; ++i) {
          int r = mf * 16 + rq + i;
          float v = fmaxf(acc2[mf][nf][i] + b2s[n], 0.f);
          sh_h[r * 512 + (((n >> 3) ^ (r & 7)) << 3) + (n & 7)] = f2bf(v);
        }
      }
  }
  __syncthreads();

  // ---- GEMM3: h3 = relu(h2 @ W3 + b3); barrier-free K-loop ----
  f32x4 acc3[8][2];
#pragma unroll
  for (int mf = 0; mf < 8; ++mf)
#pragma unroll
    for (int nf = 0; nf < 2; ++nf) acc3[mf][nf] = f32x4{0.f, 0.f, 0.f, 0.f};
#pragma unroll 2
  for (int kc = 0; kc < 16; ++kc) {
    bf16x8 bfr[2];
#pragma unroll
    for (int nf = 0; nf < 2; ++nf)
      bfr[nf] = *(const bf16x8*)(w3f + ((w * 2 + nf) * 16 + kc) * 512 + lane * 8);
#pragma unroll
    for (int mf = 0; mf < 8; ++mf) {
      int row = mf * 16 + col;
      int slot = ((kc * 32 + q8) >> 3) ^ (row & 7);
      bf16x8 a = *(const bf16x8*)(sh_h + row * 512 + slot * 8);
#pragma unroll
      for (int nf = 0; nf < 2; ++nf)
        acc3[mf][nf] = __builtin_amdgcn_mfma_f32_16x16x32_bf16(a, bfr[nf], acc3[mf][nf], 0, 0, 0);
    }
  }

  // ---- epilogue: write h ----
  {
    int rq = (lane >> 4) * 4;
#pragma unroll
    for (int mf = 0; mf < 8; ++mf)
#pragma unroll
      for (int nf = 0; nf < 2; ++nf) {
        int n = w * 32 + nf * 16 + col;
#pragma unroll
        for (int i = 0; i < 4; ++i) {
          int r = mf * 16 + rq + i;
          float v = fmaxf(acc3[mf][nf][i] + b3s[n], 0.f);
          out[HBASE + (blk * 128 + r) * 256 + n] = v;
        }
      }
  }
}

extern "C" void kernel_launch(void* const* d_in, const int* in_sizes, int n_in,
                              void* d_out, int out_size, void* d_ws, size_t ws_size,
                              hipStream_t stream) {
  const float* in_feats = (const float*)d_in[0];
  const float* Wd = (const float*)d_in[1];
  const float* bd = (const float*)d_in[2];
  const float* W1 = (const float*)d_in[3];
  const float* b1 = (const float*)d_in[4];
  const float* W2 = (const float*)d_in[5];
  const float* b2 = (const float*)d_in[6];
  const float* W3 = (const float*)d_in[7];
  const float* b3 = (const float*)d_in[8];
  float* out = (float*)d_out;
  char* ws = (char*)d_ws;
  u16*   w2f  = (u16*)(ws + WS_W2F);
  u16*   w3f  = (u16*)(ws + WS_W3F);
  u16*   w1af = (u16*)(ws + WS_W1AF);
  float* F1   = (float*)(ws + WS_F1);

  k_prep<<<1024, 256, 0, stream>>>(W1, W2, W3, w1af, w2f, w3f, out);
  k_rel<<<1024, 512, 0, stream>>>(in_feats, Wd, bd, out);
  k_f1<<<256, 512, 0, stream>>>(in_feats, b1, w1af, F1);
  k_main<<<1024, 512, 0, stream>>>(W1, b2, b3, w2f, w3f, F1, out);
}